// Round 1
// baseline (228.896 us; speedup 1.0000x reference)
//
#include <hip/hip_runtime.h>

// SimpleDialogGNN on MI355X.
// Pipeline:
//   K0 transpose_pack : W_self,W_msg -> wt_cat (N=1024 x K=2048, bf16, N-major)
//                       W_out        -> wt_out (1024x1024 bf16, N-major)
//   K1 msg_pack       : per-row windowed weighted avg; writes xcat rows
//                       [x_bf16(1024) | msg_bf16(1024)]  (M=8192 x 2048 bf16)
//   K2 gemm<2048,EPI1>: h = xcat @ wt_cat^T + b_self + b_msg;
//                       out = (t<dia_len[b]) ? h : x; r = relu(out) -> bf16
//   K3 gemm<1024,EPI2>: z = x + r @ wt_out^T + b_out -> fp32 zbuf
//   K4 ln_kernel      : LayerNorm(z) * gamma + beta -> d_out (fp32)
//
// ws layout (bytes): [0,32M) xcat (bf16)  — aliased by zbuf (fp32) after GEMM1
//                    [32M,48M) r (bf16)
//                    [48M,52M) wt_cat     [52M,54M) wt_out
// total ws required: 54 MiB.

typedef unsigned short u16;
typedef float floatx4 __attribute__((ext_vector_type(4)));
typedef short shortx8 __attribute__((ext_vector_type(8)));

#define T_ 1024
#define H_ 1024

__device__ __forceinline__ float bf2f(u16 v) {
    return __uint_as_float(((unsigned)v) << 16);
}
__device__ __forceinline__ u16 f2bf(float f) {  // round-to-nearest-even
    unsigned u = __float_as_uint(f);
    return (u16)((u + 0x7fffu + ((u >> 16) & 1u)) >> 16);
}
__device__ __forceinline__ void async16(const void* g, void* l) {
    __builtin_amdgcn_global_load_lds(
        (__attribute__((address_space(1))) void*)g,
        (__attribute__((address_space(3))) void*)l, 16, 0, 0);
}

// ---------------- K0: transpose + fp32->bf16 pack of the three weights ------
__global__ __launch_bounds__(256)
void transpose_pack(const float* __restrict__ Wself, const float* __restrict__ Wmsg,
                    const float* __restrict__ Wout,
                    u16* __restrict__ wt_cat, u16* __restrict__ wt_out)
{
    __shared__ float s[32][33];
    const int wid = blockIdx.z;
    const float* src = (wid == 0) ? Wself : ((wid == 1) ? Wmsg : Wout);
    const int n0 = blockIdx.x * 32, k0 = blockIdx.y * 32;
    const int tx = threadIdx.x & 31, ty = threadIdx.x >> 5;  // 32x8
#pragma unroll
    for (int i = 0; i < 4; ++i) {
        int k = k0 + ty + 8 * i;
        s[ty + 8 * i][tx] = src[(size_t)k * H_ + n0 + tx];
    }
    __syncthreads();
#pragma unroll
    for (int i = 0; i < 4; ++i) {
        int n = n0 + ty + 8 * i;
        u16 v = f2bf(s[tx][ty + 8 * i]);
        if (wid < 2) wt_cat[(size_t)n * 2048 + wid * 1024 + k0 + tx] = v;
        else         wt_out[(size_t)n * 1024 + k0 + tx] = v;
    }
}

// ---------------- K1: message aggregation + bf16 pack ------------------------
// block: (t-chunk of 16, b). Stages 32 rows (halo 8 each side) as bf16 in LDS.
__global__ __launch_bounds__(256)
void msg_pack(const float* __restrict__ x, const float* __restrict__ qmask,
              const int* __restrict__ dia_len, u16* __restrict__ xcat)
{
    __shared__ u16 sx[32][1024];  // 64 KiB
    const int tid = threadIdx.x;
    const int b = blockIdx.y;
    const int t0 = blockIdx.x * 16;
    const int dlen = dia_len[b];
    const int c4 = tid * 4;
    const float* xb = x + (size_t)b * T_ * H_;

    unsigned spkmask = 0;
#pragma unroll 4
    for (int r = 0; r < 32; ++r) {
        int row = t0 - 8 + r;
        row = row < 0 ? 0 : (row > T_ - 1 ? T_ - 1 : row);
        const float* q = qmask + ((size_t)b * T_ + row) * 2;
        spkmask |= (q[1] > q[0] ? 1u : 0u) << r;
        float4 v = *(const float4*)(xb + (size_t)row * H_ + c4);
        ushort4 u;
        u.x = f2bf(v.x); u.y = f2bf(v.y); u.z = f2bf(v.z); u.w = f2bf(v.w);
        *(ushort4*)&sx[r][c4] = u;
    }
    __syncthreads();

    for (int lt = 0; lt < 16; ++lt) {
        const int t = t0 + lt;
        const unsigned cs = (spkmask >> (lt + 8)) & 1u;
        float a0 = 0.f, a1 = 0.f, a2 = 0.f, a3 = 0.f;
        int cnt = 0;
#pragma unroll
        for (int o = 0; o < 17; ++o) {
            const int idx = t + o - 8;
            if (idx >= 0 && idx < dlen) {  // block-uniform branch
                const float w = (((spkmask >> (lt + o)) & 1u) == cs) ? 1.0f : 0.5f;
                ++cnt;
                ushort4 u = *(const ushort4*)&sx[lt + o][c4];
                a0 += w * bf2f(u.x); a1 += w * bf2f(u.y);
                a2 += w * bf2f(u.z); a3 += w * bf2f(u.w);
            }
        }
        const float inv = 1.0f / (float)(cnt > 0 ? cnt : 1);
        ushort4 m;
        m.x = f2bf(a0 * inv); m.y = f2bf(a1 * inv);
        m.z = f2bf(a2 * inv); m.w = f2bf(a3 * inv);
        const size_t rowg = (size_t)b * T_ + t;
        *(ushort4*)&xcat[rowg * 2048 + 1024 + c4] = m;
        *(ushort4*)&xcat[rowg * 2048 + c4] = *(const ushort4*)&sx[lt + 8][c4];
    }
}

// ---------------- K2/K3: bf16 MFMA GEMM (m97 structure) ----------------------
// A: M x K row-major bf16 (lda = K); Bt: N x K row-major bf16 (N-major).
// 128x128 tile, BK=32, 4 waves each computing 64x64 via 4x4 mfma 16x16x32.
template <int K, int EPI>
__global__ __launch_bounds__(256)
void gemm_bt(const u16* __restrict__ A, const u16* __restrict__ Bt,
             const float* __restrict__ bias1, const float* __restrict__ bias2,
             const float* __restrict__ X, const int* __restrict__ dia_len,
             u16* __restrict__ Rout, float* __restrict__ Zout)
{
    __shared__ u16 sA[128 * 32];  // 8 KiB
    __shared__ u16 sB[128 * 32];  // 8 KiB
    const int tid = threadIdx.x;
    const int bn = blockIdx.x * 128;
    const int bm = blockIdx.y * 128;
    const int wave = tid >> 6, lane = tid & 63;
    const int wr = wave >> 1, wc = wave & 1;
    const int lrow = lane & 15, lq = lane >> 4;

    // staging addresses: chunk c = i*256 + tid -> LDS byte c*16;
    // row = c>>2 (stride 64B in LDS), kk = c&3 (16B within row)
    const u16* gA0 = A + (size_t)(bm + (tid >> 2)) * K + (tid & 3) * 8;
    const u16* gA1 = gA0 + (size_t)64 * K;
    const u16* gB0 = Bt + (size_t)(bn + (tid >> 2)) * K + (tid & 3) * 8;
    const u16* gB1 = gB0 + (size_t)64 * K;
    u16* lA = sA + wave * 512;  // wave-uniform base; lane scatter = lane*16B
    u16* lB = sB + wave * 512;

    floatx4 acc[4][4];
#pragma unroll
    for (int i = 0; i < 4; ++i)
#pragma unroll
        for (int j = 0; j < 4; ++j)
            acc[i][j] = (floatx4){0.f, 0.f, 0.f, 0.f};

    const u16* pa = sA + (wr * 64 + lrow) * 32 + lq * 8;
    const u16* pb = sB + (wc * 64 + lrow) * 32 + lq * 8;

    for (int k0 = 0; k0 < K; k0 += 32) {
        __syncthreads();
        async16(gA0 + k0, lA);
        async16(gA1 + k0, lA + 2048);
        async16(gB0 + k0, lB);
        async16(gB1 + k0, lB + 2048);
        __syncthreads();  // compiler inserts vmcnt(0) drain here
        shortx8 av[4], bv[4];
#pragma unroll
        for (int i = 0; i < 4; ++i) av[i] = *(const shortx8*)(pa + i * 512);
#pragma unroll
        for (int j = 0; j < 4; ++j) bv[j] = *(const shortx8*)(pb + j * 512);
#pragma unroll
        for (int i = 0; i < 4; ++i)
#pragma unroll
            for (int j = 0; j < 4; ++j)
                acc[i][j] = __builtin_amdgcn_mfma_f32_16x16x32_bf16(
                    av[i], bv[j], acc[i][j], 0, 0, 0);
    }

    // epilogue — C/D mapping: col = lane&15, row = (lane>>4)*4 + reg
    const int dl = (EPI == 1) ? dia_len[bm >> 10] : 0;  // b uniform per block
#pragma unroll
    for (int i = 0; i < 4; ++i) {
        const int row0 = bm + wr * 64 + i * 16 + lq * 4;
#pragma unroll
        for (int j = 0; j < 4; ++j) {
            const int col = bn + wc * 64 + j * 16 + lrow;
#pragma unroll
            for (int r = 0; r < 4; ++r) {
                const int row = row0 + r;
                const float v = acc[i][j][r];
                if (EPI == 1) {
                    const float h = v + bias1[col] + bias2[col];
                    const float xv = X[(size_t)row * H_ + col];
                    const float outv = ((row & (T_ - 1)) < dl) ? h : xv;
                    Rout[(size_t)row * H_ + col] = f2bf(fmaxf(outv, 0.f));
                } else {
                    const float z = X[(size_t)row * H_ + col] + v + bias1[col];
                    Zout[(size_t)row * H_ + col] = z;
                }
            }
        }
    }
}

// ---------------- K4: LayerNorm ---------------------------------------------
__global__ __launch_bounds__(256)
void ln_kernel(const float* __restrict__ Z, const float* __restrict__ gamma,
               const float* __restrict__ beta, float* __restrict__ out)
{
    const int row = blockIdx.x;
    const int tid = threadIdx.x;
    const size_t base = (size_t)row * H_ + tid * 4;
    float4 v = *(const float4*)(Z + base);
    float s = v.x + v.y + v.z + v.w;
    float q = v.x * v.x + v.y * v.y + v.z * v.z + v.w * v.w;
#pragma unroll
    for (int off = 32; off > 0; off >>= 1) {
        s += __shfl_down(s, off);
        q += __shfl_down(q, off);
    }
    __shared__ float ps[4], pq[4];
    const int wave = tid >> 6, lane = tid & 63;
    if (lane == 0) { ps[wave] = s; pq[wave] = q; }
    __syncthreads();
    const float S = ps[0] + ps[1] + ps[2] + ps[3];
    const float Q = pq[0] + pq[1] + pq[2] + pq[3];
    const float mean = S * (1.0f / 1024.0f);
    const float var = Q * (1.0f / 1024.0f) - mean * mean;
    const float inv = rsqrtf(var + 1e-5f);
    float4 g = *(const float4*)(gamma + tid * 4);
    float4 bt = *(const float4*)(beta + tid * 4);
    float4 o;
    o.x = g.x * (v.x - mean) * inv + bt.x;
    o.y = g.y * (v.y - mean) * inv + bt.y;
    o.z = g.z * (v.z - mean) * inv + bt.z;
    o.w = g.w * (v.w - mean) * inv + bt.w;
    *(float4*)(out + base) = o;
}

// ---------------- launcher ---------------------------------------------------
extern "C" void kernel_launch(void* const* d_in, const int* in_sizes, int n_in,
                              void* d_out, int out_size, void* d_ws, size_t ws_size,
                              hipStream_t stream)
{
    (void)in_sizes; (void)n_in; (void)out_size; (void)ws_size;
    const float* x       = (const float*)d_in[0];
    const float* qmask   = (const float*)d_in[1];
    const int*   dia_len = (const int*)d_in[2];
    const float* W_msg   = (const float*)d_in[5];
    const float* b_msg   = (const float*)d_in[6];
    const float* W_self  = (const float*)d_in[7];
    const float* b_self  = (const float*)d_in[8];
    const float* W_out   = (const float*)d_in[9];
    const float* b_out   = (const float*)d_in[10];
    const float* gamma   = (const float*)d_in[11];
    const float* beta    = (const float*)d_in[12];
    float* out = (float*)d_out;

    char* ws = (char*)d_ws;
    u16*   xcat   = (u16*)ws;                           // 32 MiB
    u16*   rbuf   = (u16*)(ws + (size_t)(32u << 20));   // 16 MiB
    u16*   wt_cat = (u16*)(ws + (size_t)(48u << 20));   // 4 MiB
    u16*   wt_out = (u16*)(ws + (size_t)(52u << 20));   // 2 MiB
    float* zbuf   = (float*)ws;                         // alias xcat (safe: GEMM2 no longer reads xcat)

    transpose_pack<<<dim3(32, 32, 3), 256, 0, stream>>>(W_self, W_msg, W_out, wt_cat, wt_out);
    msg_pack<<<dim3(64, 8), 256, 0, stream>>>(x, qmask, dia_len, xcat);
    gemm_bt<2048, 1><<<dim3(8, 64), 256, 0, stream>>>(xcat, wt_cat, b_self, b_msg,
                                                      x, dia_len, rbuf, nullptr);
    gemm_bt<1024, 2><<<dim3(8, 64), 256, 0, stream>>>(rbuf, wt_out, b_out, nullptr,
                                                      x, nullptr, nullptr, zbuf);
    ln_kernel<<<dim3(8192), 256, 0, stream>>>(zbuf, gamma, beta, out);
}